// Round 20
// baseline (2416.590 us; speedup 1.0000x reference)
//
#include <hip/hip_runtime.h>
#include <math.h>

#define TPB 256

typedef __attribute__((ext_vector_type(8))) short short8;
typedef __attribute__((ext_vector_type(4))) float f32x4;

__device__ __forceinline__ float lrelu(float x){ return x > 0.f ? x : 0.2f*x; }
__device__ __forceinline__ unsigned short f2bf(float f){
  unsigned u = __float_as_uint(f);
  unsigned r = (u + 0x7FFF + ((u >> 16) & 1)) >> 16;   // RNE
  return (unsigned short)r;
}
__device__ __forceinline__ float bf2f(unsigned short h){
  return __uint_as_float(((unsigned)h) << 16);
}

// ---------------- CSR build (graph constant across layers) ----------------
__global__ void k_init_cnt(int* __restrict__ cnt, int N){
  int t = blockIdx.x*TPB + threadIdx.x;
  if (t < 4*N) cnt[t] = (t < 3*N) ? 1 : 0;  // GAT counts start at 1 (self-loop)
}

__global__ void k_count(const int* __restrict__ ei, int* __restrict__ cnt, int N, int E){
  int t = blockIdx.x*TPB + threadIdx.x;
  if (t >= 3*E) return;
  int r = t / E, e = t - r*E;
  int dst = ei[(r*2+1)*E + e];
  atomicAdd(&cnt[r*N + dst], 1);
  atomicAdd(&cnt[3*N + dst], 1);
}

// scan + cursor init fused
__global__ void k_scan4(const int* __restrict__ cnt, int* __restrict__ rp,
                        int* __restrict__ cur, int N){
  __shared__ int sh[1024];
  __shared__ int carry;
  int a = blockIdx.x;
  const int* c = cnt + a*N;
  int* r = rp + a*(N+1);
  if (threadIdx.x == 0) carry = 0;
  __syncthreads();
  for (int base = 0; base < N; base += 1024){
    int idx = base + threadIdx.x;
    int v = (idx < N) ? c[idx] : 0;
    sh[threadIdx.x] = v;
    __syncthreads();
    for (int off = 1; off < 1024; off <<= 1){
      int t = (threadIdx.x >= off) ? sh[threadIdx.x - off] : 0;
      __syncthreads();
      sh[threadIdx.x] += t;
      __syncthreads();
    }
    if (idx < N){
      int ex = carry + sh[threadIdx.x] - v;   // exclusive
      r[idx] = ex;
      cur[a*N + idx] = ex;
    }
    __syncthreads();
    if (threadIdx.x == 0) carry += sh[1023];
    __syncthreads();
  }
  if (threadIdx.x == 0) r[N] = carry;
}

__global__ void k_scatter(const int* __restrict__ ei, int* __restrict__ cur,
                          int* __restrict__ idx_gat,
                          int* __restrict__ idx_hgt, int* __restrict__ idx_hgt_dst,
                          int N, int E){
  int t = blockIdx.x*TPB + threadIdx.x;
  int EN = E + N;
  if (t < 3*E){
    int r = t / E, e = t - r*E;
    int src = ei[(r*2)*E + e];
    int dst = ei[(r*2+1)*E + e];
    int pg = atomicAdd(&cur[r*N + dst], 1);
    idx_gat[r*EN + pg] = src;
    int ph = atomicAdd(&cur[3*N + dst], 1);
    idx_hgt[ph] = r*N + src;           // packed (rel,src)
    idx_hgt_dst[ph] = dst;
  } else if (t < 3*E + 3*N){
    int tt = t - 3*E;
    int r = tt / N, i = tt - r*N;
    int pg = atomicAdd(&cur[r*N + i], 1);
    idx_gat[r*EN + pg] = i;            // self loop
  }
}

// ---------------- one-shot conversions: weights -> bf16 WT; x -> (hi,lo) bf16 ----------------
__device__ __forceinline__ void cvtw_one(const float* W, unsigned short* WT, int K, int u){
  int m = u / (96*K);
  int rem = u - m*96*K;
  int o = rem / K;
  int c = rem - o*K;
  WT[u] = f2bf(W[((size_t)m*K + c)*96 + o]);
}
__global__ void k_cvt_all(const float* __restrict__ x, const float* __restrict__ gat0_W,
                          const float* __restrict__ gat_W, const float* __restrict__ proj_W,
                          const float* __restrict__ hout_W,
                          unsigned short* __restrict__ x_hi, unsigned short* __restrict__ x_lo,
                          unsigned short* __restrict__ Wgat0T,
                          unsigned short* __restrict__ WgatT, unsigned short* __restrict__ WprojT,
                          unsigned short* __restrict__ WhoutT, int N){
  int t = blockIdx.x*TPB + threadIdx.x;
  int n0 = N*32, n1 = 3*96*32, n2 = 9*96*96, n3 = 2*96*32, n4 = 2*96*96;
  if (t < n0){
    float v = x[t];
    unsigned short hh = f2bf(v);
    x_hi[t] = hh;
    x_lo[t] = f2bf(v - bf2f(hh));
    return;
  }
  t -= n0;
  if (t < n1){ cvtw_one(gat0_W, Wgat0T, 32, t); return; }
  t -= n1;
  if (t < n2){ cvtw_one(gat_W, WgatT, 96, t); return; }
  t -= n2;
  if (t < n3){ cvtw_one(proj_W, WprojT, 32, t); return; }
  t -= n3;
  if (t < n4){ cvtw_one(hout_W, WhoutT, 96, t); }
}

// ---------------- split-A MFMA GEMM: 512 thr / 8 waves x 16 rows = 128-row tile ----------------
// Optional fused GAT att-dots (shfl butterfly) OR fused skip-mix + BN stats (mixh != nullptr).
__global__ __launch_bounds__(512) void k_gemm_mfma(
    const unsigned short* __restrict__ Ahi, const unsigned short* __restrict__ Alo,
    const unsigned short* __restrict__ WT,
    const float* __restrict__ bias, float* __restrict__ Cf,
    unsigned short* __restrict__ Cb, int bf16_from, int n, int K,
    const float* __restrict__ att, float* __restrict__ asrc, float* __restrict__ adst,
    const float* __restrict__ mixh, const float* __restrict__ skipp,
    float* __restrict__ stats){
  __shared__ unsigned short WlT[96*104];         // [col][K+8] padded
  __shared__ float sl1[96], sl2[96];
  const int Kp = K + 8;
  int mat = blockIdx.y;
  const unsigned short* Wm = WT + (size_t)mat*96*K;
  int chunks = 96*(K/8);
  for (int idx = threadIdx.x; idx < chunks; idx += 512){
    int col = idx/(K/8), kc = idx - col*(K/8);
    *reinterpret_cast<uint4*>(&WlT[col*Kp + kc*8]) =
      *reinterpret_cast<const uint4*>(&Wm[(size_t)col*K + kc*8]);
  }
  if (mixh && threadIdx.x < 96){ sl1[threadIdx.x] = 0.f; sl2[threadIdx.x] = 0.f; }
  __syncthreads();

  int wave = threadIdx.x >> 6, lane = threadIdx.x & 63;
  int l15 = lane & 15, l4 = lane >> 4;
  int rowbase = blockIdx.x*128 + wave*16;

  f32x4 acc[6];
  #pragma unroll
  for (int ct = 0; ct < 6; ct++){
    f32x4 z = {0.f, 0.f, 0.f, 0.f};
    acc[ct] = z;
  }

  int arow = rowbase + l15;
  for (int ks = 0; ks < K; ks += 32){
    short8 ahi, alo;
    if (arow < n){
      size_t off = (size_t)arow*K + ks + l4*8;
      ahi = *reinterpret_cast<const short8*>(Ahi + off);
      alo = *reinterpret_cast<const short8*>(Alo + off);
    } else {
      short8 z = {0,0,0,0,0,0,0,0};
      ahi = z; alo = z;
    }
    #pragma unroll
    for (int ct = 0; ct < 6; ct++){
      short8 b = *reinterpret_cast<const short8*>(&WlT[(ct*16 + l15)*Kp + ks + l4*8]);
      acc[ct] = __builtin_amdgcn_mfma_f32_16x16x32_bf16(alo, b, acc[ct], 0, 0, 0);
      acc[ct] = __builtin_amdgcn_mfma_f32_16x16x32_bf16(ahi, b, acc[ct], 0, 0, 0);
    }
  }

  if (att){   // fused GAT att-dots from raw fp32 accs (GAT gemm has bias=nullptr)
    const float* apS = att + mat*192;
    const float* apD = apS + 96;
    float wS[6], wD[6];
    #pragma unroll
    for (int ct = 0; ct < 6; ct++){ wS[ct] = apS[ct*16 + l15]; wD[ct] = apD[ct*16 + l15]; }
    #pragma unroll
    for (int r = 0; r < 4; r++){
      float s0 = 0.f, s1 = 0.f, d0 = 0.f, d1 = 0.f;
      #pragma unroll
      for (int ct = 0; ct < 3; ct++){
        float v = acc[ct][r];
        s0 += v*wS[ct]; d0 += v*wD[ct];
      }
      #pragma unroll
      for (int ct = 3; ct < 6; ct++){
        float v = acc[ct][r];
        s1 += v*wS[ct]; d1 += v*wD[ct];
      }
      #pragma unroll
      for (int m = 1; m < 16; m <<= 1){
        s0 += __shfl_xor(s0, m); s1 += __shfl_xor(s1, m);
        d0 += __shfl_xor(d0, m); d1 += __shfl_xor(d1, m);
      }
      if (l15 == 0){
        int row = rowbase + l4*4 + r;
        if (row < n){
          reinterpret_cast<float2*>(asrc)[(size_t)mat*n + row] = make_float2(s0, s1);
          reinterpret_cast<float2*>(adst)[(size_t)mat*n + row] = make_float2(d0, d1);
        }
      }
    }
  }

  // C/D layout (m89): col = lane&15, row = (lane>>4)*4 + reg
  if (mixh){   // hout path: skip-mix + BN stats epilogue (uniform work -> barrier safe)
    float sk = 1.f / (1.f + __expf(-skipp[0]));
    #pragma unroll
    for (int ct = 0; ct < 6; ct++){
      int col = ct*16 + l15;
      float bv = bias[mat*96 + col];
      #pragma unroll
      for (int r = 0; r < 4; r++){
        int row = rowbase + l4*4 + r;
        if (row < n){
          float v = acc[ct][r] + bv;
          v = sk*v + (1.f - sk)*mixh[(size_t)row*96 + col];
          Cf[(size_t)row*96 + col] = v;
          atomicAdd(&sl1[col], v);
          atomicAdd(&sl2[col], v*v);
        }
      }
    }
    __syncthreads();
    if (threadIdx.x < 96){
      atomicAdd(&stats[threadIdx.x], sl1[threadIdx.x]);
      atomicAdd(&stats[96 + threadIdx.x], sl2[threadIdx.x]);
    }
  } else {
    bool as_bf = (mat >= bf16_from);
    #pragma unroll
    for (int ct = 0; ct < 6; ct++){
      int col = ct*16 + l15;
      float bv = bias ? bias[mat*96 + col] : 0.f;
      #pragma unroll
      for (int r = 0; r < 4; r++){
        int row = rowbase + l4*4 + r;
        if (row < n){
          float v = acc[ct][r] + bv;
          if (as_bf)
            Cb[(size_t)(mat - bf16_from)*n*96 + (size_t)row*96 + col] = f2bf(v);
          else
            Cf[(size_t)mat*n*96 + (size_t)row*96 + col] = v;
        }
      }
    }
  }
}

// ---------------- HGT effective-weight prep (both layers, one launch) ----------
__global__ void k_prep(const float* __restrict__ kqv_W, const float* __restrict__ kqv_b,
                       const float* __restrict__ a_rel, const float* __restrict__ m_rel,
                       const float* __restrict__ p_rel,
                       unsigned short* __restrict__ WbigT, float* __restrict__ bbig){
  int layer = blockIdx.y;
  const float* kW   = kqv_W + (size_t)layer*3*96*96;
  const float* kb   = kqv_b + layer*3*96;
  const float* arel = a_rel + (size_t)layer*3*6*256;
  const float* mrel = m_rel + (size_t)layer*3*6*256;
  const float* prel = p_rel + layer*18;
  unsigned short* WT = WbigT + (size_t)layer*7*96*96;
  float* bb = bbig + layer*7*96;
  int t = blockIdx.x*TPB + threadIdx.x;
  const int total = 7*96*96;
  if (t < total){
    int m = t / (96*96);
    int rem = t - m*(96*96);
    int o = rem / 96;        // output col
    int c = rem - o*96;      // input k
    float val;
    if (m == 0){
      val = kW[(size_t)96*96 + c*96 + o];            // q weights
    } else {
      int r = (m - 1) % 3;
      bool isV = m >= 4;
      const float* base = isV ? mrel : arel;         // [3][6][16][16]
      const float* wsrc = kW + (size_t)(isV ? 2 : 0)*96*96;
      int h = o >> 4, ff = o & 15;
      float s = 0.f;
      #pragma unroll
      for (int d = 0; d < 16; d++)
        s += wsrc[c*96 + h*16 + d] * base[(size_t)((r*6 + h)*16 + d)*16 + ff];
      if (!isV) s *= 0.25f * prel[r*6 + h];
      val = s;
    }
    WT[t] = f2bf(val);       // t == (m*96 + o)*96 + c
  } else if (t < total + 7*96){
    int tt = t - total;
    int m = tt / 96, o = tt - m*96;
    float val;
    if (m == 0){
      val = kb[96 + o];
    } else {
      int r = (m - 1) % 3;
      bool isV = m >= 4;
      const float* base = isV ? mrel : arel;
      const float* bsrc = kb + (isV ? 2 : 0)*96;
      int h = o >> 4, ff = o & 15;
      float s = 0.f;
      #pragma unroll
      for (int d = 0; d < 16; d++)
        s += bsrc[h*16 + d] * base[(size_t)((r*6 + h)*16 + d)*16 + ff];
      if (!isV) s *= 0.25f * prel[r*6 + h];
      val = s;
    }
    bb[tt] = val;
  }
}

// ---------------- GAT fused v6: v4 body + barrier-free per-wave global stats atomics ----
__global__ __launch_bounds__(TPB) void k_gat_fused(const float* __restrict__ asrc,
                        const float* __restrict__ adst, const unsigned short* __restrict__ hp,
                        const int* __restrict__ rowptr, const int* __restrict__ idxg,
                        const float* __restrict__ b3, float* __restrict__ pre,
                        float* __restrict__ stats, int n, int EN){
  int wid = (blockIdx.x*TPB + threadIdx.x) >> 6;   // wave id = node
  if (wid >= n) return;
  int lane = threadIdx.x & 63;

  // phase 1: prefetch all 3 relations' first batches (loads issue together)
  int s0[3], s1[3], cnt0[3], src0[3];
  float2 av0[3], adv[3];
  #pragma unroll
  for (int r = 0; r < 3; r++){
    const int* rp = rowptr + r*(n+1);
    s0[r] = rp[wid]; s1[r] = rp[wid+1];
    cnt0[r] = min(64, s1[r] - s0[r]);
    adv[r] = (reinterpret_cast<const float2*>(adst) + (size_t)r*n)[wid];
  }
  #pragma unroll
  for (int r = 0; r < 3; r++)
    src0[r] = (lane < cnt0[r]) ? idxg[(size_t)r*EN + s0[r] + lane] : 0;
  #pragma unroll
  for (int r = 0; r < 3; r++)
    av0[r] = (lane < cnt0[r]) ? (reinterpret_cast<const float2*>(asrc) + (size_t)r*n)[src0[r]]
                              : make_float2(0.f, 0.f);

  float comb_a = 0.f, comb_b = 0.f;
  #pragma unroll
  for (int r = 0; r < 3; r++){
    const unsigned short* hpb = hp + (size_t)r*n*96;
    float w0_l = 0.f, w1_l = 0.f;
    if (lane < cnt0[r]){
      w0_l = __expf(fminf(lrelu(av0[r].x + adv[r].x), 80.f));
      w1_l = __expf(fminf(lrelu(av0[r].y + adv[r].y), 80.f));
    }
    float acc_a = 0.f, acc_b = 0.f, ss0 = 0.f, ss1 = 0.f;
    int cnt = cnt0[r];
    int src_l = src0[r];
    int base = s0[r];
    while (true){
      int j = 0;
      for (; j + 4 <= cnt; j += 4){
        int sa = __shfl(src_l, j),   sb = __shfl(src_l, j+1);
        int sc = __shfl(src_l, j+2), sd = __shfl(src_l, j+3);
        const unsigned short* ra = hpb + (size_t)sa*96;
        const unsigned short* rb = hpb + (size_t)sb*96;
        const unsigned short* rc = hpb + (size_t)sc*96;
        const unsigned short* rd = hpb + (size_t)sd*96;
        float vaa = bf2f(ra[lane]), vab = bf2f(rb[lane]);
        float vac = bf2f(rc[lane]), vad = bf2f(rd[lane]);
        float vba = 0.f, vbb = 0.f, vbc = 0.f, vbd = 0.f;
        if (lane < 32){
          vba = bf2f(ra[64+lane]); vbb = bf2f(rb[64+lane]);
          vbc = bf2f(rc[64+lane]); vbd = bf2f(rd[64+lane]);
        }
        float w0a = __shfl(w0_l, j),   w1a = __shfl(w1_l, j);
        float w0b = __shfl(w0_l, j+1), w1b = __shfl(w1_l, j+1);
        float w0c = __shfl(w0_l, j+2), w1c = __shfl(w1_l, j+2);
        float w0d = __shfl(w0_l, j+3), w1d = __shfl(w1_l, j+3);
        float waa = (lane < 48) ? w0a : w1a;
        float wab = (lane < 48) ? w0b : w1b;
        float wac = (lane < 48) ? w0c : w1c;
        float wad = (lane < 48) ? w0d : w1d;
        acc_a += waa*vaa; acc_b += w1a*vba; ss0 += w0a; ss1 += w1a;
        acc_a += wab*vab; acc_b += w1b*vbb; ss0 += w0b; ss1 += w1b;
        acc_a += wac*vac; acc_b += w1c*vbc; ss0 += w0c; ss1 += w1c;
        acc_a += wad*vad; acc_b += w1d*vbd; ss0 += w0d; ss1 += w1d;
      }
      for (; j < cnt; j++){
        int sa = __shfl(src_l, j);
        const unsigned short* ra = hpb + (size_t)sa*96;
        float vaa = bf2f(ra[lane]);
        float vba = (lane < 32) ? bf2f(ra[64+lane]) : 0.f;
        float w0a = __shfl(w0_l, j), w1a = __shfl(w1_l, j);
        float waa = (lane < 48) ? w0a : w1a;
        acc_a += waa*vaa; acc_b += w1a*vba; ss0 += w0a; ss1 += w1a;
      }
      base += 64;
      if (base >= s1[r]) break;
      cnt = min(64, s1[r] - base);         // rare: degree > 64
      src_l = 0; w0_l = 0.f; w1_l = 0.f;
      if (lane < cnt){
        src_l = idxg[(size_t)r*EN + base + lane];
        float2 av = (reinterpret_cast<const float2*>(asrc) + (size_t)r*n)[src_l];
        w0_l = __expf(fminf(lrelu(av.x + adv[r].x), 80.f));
        w1_l = __expf(fminf(lrelu(av.y + adv[r].y), 80.f));
      }
    }
    comb_a += acc_a / ((lane < 48) ? ss0 : ss1);   // self-loop => non-empty
    comb_b += acc_b / ss1;
  }
  comb_a += b3[lane] + b3[96 + lane] + b3[192 + lane];
  float* pr = pre + (size_t)wid*96;
  pr[lane] = comb_a;
  atomicAdd(&stats[lane], comb_a);
  atomicAdd(&stats[96 + lane], comb_a*comb_a);
  if (lane < 32){
    comb_b += b3[64 + lane] + b3[160 + lane] + b3[256 + lane];
    pr[64 + lane] = comb_b;
    atomicAdd(&stats[64 + lane], comb_b);
    atomicAdd(&stats[96 + 64 + lane], comb_b*comb_b);
  }
}

// ---------------- apply: BN finalize + lrelu; writes fp32 h AND (hi,lo) bf16 h ----------------
__global__ void k_apply2(float* __restrict__ h, unsigned short* __restrict__ h_hi,
                         unsigned short* __restrict__ h_lo,
                         const float* __restrict__ pre,
                         const float* __restrict__ stats, const float* __restrict__ gamma,
                         const float* __restrict__ beta, const float* __restrict__ inj,
                         int res, int total, float inv_n){
  int idx = blockIdx.x*TPB + threadIdx.x;
  if (idx >= total) return;
  int c = idx % 96;
  float mean = stats[c] * inv_n;
  float var  = stats[96 + c] * inv_n - mean*mean;
  float sc   = gamma[c] * rsqrtf(var + 1e-5f);
  float sh   = beta[c] - mean*sc;
  float v = sc*pre[idx] + sh;
  if (inj) v += inj[idx];
  if (res) v += h[idx];
  v = lrelu(v);
  h[idx] = v;
  unsigned short hh = f2bf(v);
  h_hi[idx] = hh;
  h_lo[idx] = f2bf(v - bf2f(hh));
}

// ---------------- HGT phase A: per-(slot,head) edge weights (scale pre-folded) ----------------
__global__ void k_hgt_w(const float* __restrict__ q, const float* __restrict__ Kb,
                        const int* __restrict__ idxh, const int* __restrict__ idxh_dst,
                        float* __restrict__ wbuf, int n, int totE){
  int t = blockIdx.x*TPB + threadIdx.x;
  if (t >= totE*6) return;
  int slot = t / 6, h = t - slot*6;
  int packed = idxh[slot];
  int dst = idxh_dst[slot];
  const float4* kp = reinterpret_cast<const float4*>(Kb + (size_t)packed*96 + h*16);
  const float4* qp = reinterpret_cast<const float4*>(q + (size_t)dst*96 + h*16);
  float dot = 0.f;
  #pragma unroll
  for (int w = 0; w < 4; w++){
    float4 kv = kp[w], qv = qp[w];
    dot += kv.x*qv.x + kv.y*qv.y + kv.z*qv.z + kv.w*qv.w;
  }
  wbuf[t] = __expf(fminf(dot, 80.f));
}

// ---------------- HGT fused gather v2: wave per node; unroll-4 j-loop; bf16 V; + GELU ----------
__global__ __launch_bounds__(TPB) void k_hgt_fused(const float* __restrict__ wbuf,
                        const unsigned short* __restrict__ Vb, const int* __restrict__ rp4,
                        const int* __restrict__ idxh,
                        unsigned short* __restrict__ aux_hi, unsigned short* __restrict__ aux_lo,
                        int n){
  int wid = (blockIdx.x*TPB + threadIdx.x) >> 6;
  if (wid >= n) return;
  int lane = threadIdx.x & 63;
  const int* rp = rp4 + 3*(n+1);
  int s0 = rp[wid], s1 = rp[wid+1];
  int ha = lane >> 4;                         // head for col=lane (0..3)
  int hb = lane >> 4;                         // head sel for col 64+lane
  float acc_a = 0.f, acc_b = 0.f, ss_a = 0.f, ss_b = 0.f;
  for (int base = s0; base < s1; base += 64){
    int cnt = min(64, s1 - base);
    int pk = 0; float w0=0.f,w1=0.f,w2=0.f,w3=0.f,w4=0.f,w5=0.f;
    if (lane < cnt){
      int slot = base + lane;
      pk = idxh[slot];
      const float2* wp = reinterpret_cast<const float2*>(wbuf + (size_t)slot*6);
      float2 p0 = wp[0], p1 = wp[1], p2 = wp[2];
      w0=p0.x; w1=p0.y; w2=p1.x; w3=p1.y; w4=p2.x; w5=p2.y;
    }
    int j = 0;
    for (; j + 4 <= cnt; j += 4){
      int pa = __shfl(pk, j),   pb = __shfl(pk, j+1);
      int pc = __shfl(pk, j+2), pd = __shfl(pk, j+3);
      const unsigned short* ra = Vb + (size_t)pa*96;
      const unsigned short* rb = Vb + (size_t)pb*96;
      const unsigned short* rc = Vb + (size_t)pc*96;
      const unsigned short* rd = Vb + (size_t)pd*96;
      float vaa = bf2f(ra[lane]), vab = bf2f(rb[lane]);
      float vac = bf2f(rc[lane]), vad = bf2f(rd[lane]);
      float vba = 0.f, vbb = 0.f, vbc = 0.f, vbd = 0.f;
      if (lane < 32){
        vba = bf2f(ra[64+lane]); vbb = bf2f(rb[64+lane]);
        vbc = bf2f(rc[64+lane]); vbd = bf2f(rd[64+lane]);
      }
      #pragma unroll
      for (int u = 0; u < 4; u++){
        int jj = j + u;
        float b0=__shfl(w0,jj), b1=__shfl(w1,jj), b2=__shfl(w2,jj),
              b3v=__shfl(w3,jj), b4=__shfl(w4,jj), b5=__shfl(w5,jj);
        float va = (u==0)?vaa:(u==1)?vab:(u==2)?vac:vad;
        float vb = (u==0)?vba:(u==1)?vbb:(u==2)?vbc:vbd;
        float wa = (ha==0) ? b0 : ((ha==1) ? b1 : ((ha==2) ? b2 : b3v));
        float wb = (hb == 0) ? b4 : b5;
        acc_a += wa*va; ss_a += wa;
        acc_b += wb*vb; ss_b += wb;
      }
    }
    for (; j < cnt; j++){
      int packed = __shfl(pk, j);
      float b0=__shfl(w0,j), b1=__shfl(w1,j), b2=__shfl(w2,j),
            b3v=__shfl(w3,j), b4=__shfl(w4,j), b5=__shfl(w5,j);
      const unsigned short* row = Vb + (size_t)packed*96;
      float va = bf2f(row[lane]);
      float vb = (lane < 32) ? bf2f(row[64 + lane]) : 0.f;
      float wa = (ha==0) ? b0 : ((ha==1) ? b1 : ((ha==2) ? b2 : b3v));
      float wb = (hb == 0) ? b4 : b5;
      acc_a += wa*va; ss_a += wa;
      acc_b += wb*vb; ss_b += wb;
    }
  }
  float xa = (s1 > s0) ? acc_a/ss_a : 0.f;
  float ga = 0.5f*xa*(1.f + erff(xa*0.70710678118654752f));
  size_t base_o = (size_t)wid*96;
  unsigned short hh = f2bf(ga);
  aux_hi[base_o + lane] = hh;
  aux_lo[base_o + lane] = f2bf(ga - bf2f(hh));
  if (lane < 32){
    float xb = (s1 > s0) ? acc_b/ss_b : 0.f;
    float gb = 0.5f*xb*(1.f + erff(xb*0.70710678118654752f));
    unsigned short hb2 = f2bf(gb);
    aux_hi[base_o + 64 + lane] = hb2;
    aux_lo[base_o + 64 + lane] = f2bf(gb - bf2f(hb2));
  }
}

// ---------------- final linear ----------------
__global__ void k_final_lin(const float* __restrict__ h, const float* __restrict__ w,
                            const float* __restrict__ b, float* __restrict__ out, int N){
  int i = blockIdx.x*TPB + threadIdx.x;
  if (i >= N) return;
  const float4* hr = reinterpret_cast<const float4*>(h + (size_t)i*96);
  const float4* wr = reinterpret_cast<const float4*>(w);
  float acc = 0.f;
  #pragma unroll
  for (int c = 0; c < 24; c++){
    float4 a = hr[c], q = wr[c];
    acc += a.x*q.x + a.y*q.y + a.z*q.z + a.w*q.w;
  }
  out[i] = acc + b[0];
}

// =====================================================================
extern "C" void kernel_launch(void* const* d_in, const int* in_sizes, int n_in,
                              void* d_out, int out_size, void* d_ws, size_t ws_size,
                              hipStream_t stream){
  const float* x        = (const float*)d_in[0];
  const int*   ei       = (const int*)  d_in[1];
  const float* gat0_W   = (const float*)d_in[2];
  const float* gat0_att = (const float*)d_in[3];
  const float* gat0_b   = (const float*)d_in[4];
  const float* gat_W    = (const float*)d_in[5];
  const float* gat_att  = (const float*)d_in[6];
  const float* gat_b    = (const float*)d_in[7];
  const float* bn_g     = (const float*)d_in[8];
  const float* bn_b     = (const float*)d_in[9];
  const float* kqv_W    = (const float*)d_in[10];
  const float* kqv_b    = (const float*)d_in[11];
  const float* a_rel    = (const float*)d_in[12];
  const float* m_rel    = (const float*)d_in[13];
  const float* p_rel    = (const float*)d_in[14];
  const float* hout_W   = (const float*)d_in[15];
  const float* hout_b   = (const float*)d_in[16];
  const float* skip     = (const float*)d_in[17];
  const float* proj_W   = (const float*)d_in[18];
  const float* proj_b   = (const float*)d_in[19];
  const float* lin_W    = (const float*)d_in[20];
  const float* lin_b    = (const float*)d_in[21];
  float* out = (float*)d_out;

  const int N = in_sizes[0] / 32;
  const int E = in_sizes[1] / 6;
  const int EN = E + N;
  const size_t NH = (size_t)N * 96;
  const int nh = (int)NH;
  const float inv_n = 1.f / (float)N;

  // ---- workspace layout (floats, then bf16, then ints) ----
  float* f = (float*)d_ws;
  float* h_buf = f;  f += NH;
  float* pre   = f;  f += NH;        // aliased as wbuf (HGT phase A->B window)
  float* big   = f;  f += 4*NH;      // HGT fp32: q, K0..2
  float* inj2  = f;  f += 2*NH;      // proj injections (precomputed)
  float* asrc  = f;  f += (size_t)3*N*2;
  float* adst  = f;  f += (size_t)3*N*2;
  float* stats = f;  f += 6*192;     // 6 BN slots of (sum[96], sumsq[96])
  float* bbig  = f;  f += 2*7*96;
  unsigned short* us = (unsigned short*)f;
  unsigned short* gbf    = us;  us += 3*NH;        // bf16 gather src: GAT hp[3] | HGT V[3]
  unsigned short* h_hi   = us;  us += NH;
  unsigned short* h_lo   = us;  us += NH;
  unsigned short* x_hi   = us;  us += (size_t)N*32;
  unsigned short* x_lo   = us;  us += (size_t)N*32;
  unsigned short* aux_hi = us;  us += NH;
  unsigned short* aux_lo = us;  us += NH;
  unsigned short* WbigT  = us;  us += 2*7*96*96;
  unsigned short* Wgat0T = us;  us += 3*96*32;
  unsigned short* WgatT  = us;  us += 9*96*96;
  unsigned short* WprojT = us;  us += 2*96*32;
  unsigned short* WhoutT = us;  us += 2*96*96;
  us += (us - (unsigned short*)f) & 1;             // realign to 4B
  int* ip = (int*)us;
  int* cnt     = ip;  ip += 4*N;
  int* rowptr  = ip;  ip += 4*(N+1);
  int* cursor  = ip;  ip += 4*N;
  int* idx_gat     = ip;  ip += 3*EN;
  int* idx_hgt     = ip;  ip += 3*E;
  int* idx_hgt_dst = ip;  ip += 3*E;
  float* wbuf = pre;                 // 3E*6 = 1.8M floats <= NH

  auto g1 = [](int n){ return dim3((n + TPB - 1)/TPB); };
  const int gx2 = (N + 127)/128;              // MFMA GEMM row-tiles
  const dim3 mg3(gx2, 3);                     // 3-mat MFMA grid (GAT)
  const dim3 mg7(gx2, 7);                     // 7-mat MFMA grid (HGT qKV)
  const dim3 mg2(gx2, 2);                     // 2-mat MFMA grid (proj)
  const dim3 mg1(gx2, 1);                     // 1-mat MFMA grid (hout)
  const dim3 pg(g1(7*96*96 + 7*96).x, 2);     // prep grid (both HGT layers)
  const int wave_blocks = (N + 3)/4;          // 4 waves (nodes) per 256-block
  const int cvt_total = N*32 + 3*96*32 + 9*96*96 + 2*96*32 + 2*96*96;

  // ---- CSR build + stats zero + one-time conversions + prep + proj injections ----
  hipMemsetAsync(stats, 0, 6*192*sizeof(float), stream);
  k_init_cnt<<<g1(4*N),     TPB, 0, stream>>>(cnt, N);
  k_count   <<<g1(3*E),     TPB, 0, stream>>>(ei, cnt, N, E);
  k_scan4   <<<4,          1024, 0, stream>>>(cnt, rowptr, cursor, N);
  k_scatter <<<g1(3*E+3*N), TPB, 0, stream>>>(ei, cursor, idx_gat, idx_hgt, idx_hgt_dst, N, E);
  k_cvt_all <<<g1(cvt_total), TPB, 0, stream>>>(x, gat0_W, gat_W, proj_W, hout_W,
                                                x_hi, x_lo, Wgat0T, WgatT, WprojT, WhoutT, N);
  k_prep    <<<pg, TPB, 0, stream>>>(kqv_W, kqv_b, a_rel, m_rel, p_rel, WbigT, bbig);
  k_gemm_mfma<<<mg2, 512, 0, stream>>>(x_hi, x_lo, WprojT, proj_b, inj2, nullptr, 99, N, 32,
                                       nullptr, nullptr, nullptr, nullptr, nullptr, nullptr);

  auto run_hgt = [&](int idx, int bnidx){
    // mats 0..3 (q,K0..2) -> fp32 big; mats 4..6 (V0..2) -> bf16 gbf
    k_gemm_mfma<<<mg7, 512, 0, stream>>>(h_hi, h_lo, WbigT + (size_t)idx*7*96*96,
                                         bbig + idx*7*96, big, gbf, 4, N, 96,
                                         nullptr, nullptr, nullptr, nullptr, nullptr, nullptr);
    k_hgt_w    <<<g1(3*E*6), TPB, 0, stream>>>(big, big + NH, idx_hgt, idx_hgt_dst, wbuf, N, 3*E);
    k_hgt_fused<<<wave_blocks, TPB, 0, stream>>>(wbuf, gbf, rowptr, idx_hgt,
                                                 aux_hi, aux_lo, N);
    // hout GEMM with fused skip-mix + BN stats epilogue
    k_gemm_mfma<<<mg1, 512, 0, stream>>>(aux_hi, aux_lo, WhoutT + (size_t)idx*96*96,
                                         hout_b + idx*96, pre, nullptr, 99, N, 96,
                                         nullptr, nullptr, nullptr,
                                         h_buf, skip + idx, stats + bnidx*192);
    k_apply2   <<<g1(nh), TPB, 0, stream>>>(h_buf, h_hi, h_lo, pre, stats + bnidx*192,
                                            bn_g + bnidx*96, bn_b + bnidx*96, nullptr, 1, nh, inv_n);
  };

  // ---- GAT layer 0 (input dim 32, no residual) ----
  k_gemm_mfma<<<mg3, 512, 0, stream>>>(x_hi, x_lo, Wgat0T, nullptr, nullptr, gbf, 0, N, 32,
                                       gat0_att, asrc, adst, nullptr, nullptr, nullptr);
  k_gat_fused<<<wave_blocks, TPB, 0, stream>>>(asrc, adst, gbf, rowptr, idx_gat, gat0_b,
                                               pre, stats, N, EN);
  k_apply2   <<<g1(nh), TPB, 0, stream>>>(h_buf, h_hi, h_lo, pre, stats,
                                          bn_g, bn_b, nullptr, 0, nh, inv_n);

  // ---- GAT layers 1..3 ----
  for (int i = 0; i < 3; i++){
    int li = i + 1;
    int bnidx = 1 + i;
    k_gemm_mfma<<<mg3, 512, 0, stream>>>(h_hi, h_lo, WgatT + (size_t)i*3*96*96, nullptr,
                                         nullptr, gbf, 0, N, 96,
                                         gat_att + i*3*192, asrc, adst, nullptr, nullptr, nullptr);
    k_gat_fused<<<wave_blocks, TPB, 0, stream>>>(asrc, adst, gbf, rowptr, idx_gat,
                                                 gat_b + i*3*96, pre, stats + bnidx*192, N, EN);
    const float* inj = (li >= 2) ? (inj2 + (size_t)(li-2)*NH) : nullptr;
    k_apply2<<<g1(nh), TPB, 0, stream>>>(h_buf, h_hi, h_lo, pre, stats + bnidx*192,
                                         bn_g + bnidx*96, bn_b + bnidx*96, inj, 1, nh, inv_n);
    if (li == 1) run_hgt(0, 4);
  }
  run_hgt(1, 5);

  k_final_lin<<<g1(N), TPB, 0, stream>>>(h_buf, lin_W, lin_b, out, N);
}

// Round 21
// 693.069 us; speedup vs baseline: 3.4868x; 3.4868x over previous
//
#include <hip/hip_runtime.h>
#include <math.h>

#define TPB 256

typedef __attribute__((ext_vector_type(8))) short short8;
typedef __attribute__((ext_vector_type(4))) float f32x4;

__device__ __forceinline__ float lrelu(float x){ return x > 0.f ? x : 0.2f*x; }
__device__ __forceinline__ unsigned short f2bf(float f){
  unsigned u = __float_as_uint(f);
  unsigned r = (u + 0x7FFF + ((u >> 16) & 1)) >> 16;   // RNE
  return (unsigned short)r;
}
__device__ __forceinline__ float bf2f(unsigned short h){
  return __uint_as_float(((unsigned)h) << 16);
}

// ---------------- CSR build (graph constant across layers) ----------------
__global__ void k_init_cnt(int* __restrict__ cnt, int N){
  int t = blockIdx.x*TPB + threadIdx.x;
  if (t < 4*N) cnt[t] = (t < 3*N) ? 1 : 0;  // GAT counts start at 1 (self-loop)
}

__global__ void k_count(const int* __restrict__ ei, int* __restrict__ cnt, int N, int E){
  int t = blockIdx.x*TPB + threadIdx.x;
  if (t >= 3*E) return;
  int r = t / E, e = t - r*E;
  int dst = ei[(r*2+1)*E + e];
  atomicAdd(&cnt[r*N + dst], 1);
  atomicAdd(&cnt[3*N + dst], 1);
}

// scan + cursor init fused
__global__ void k_scan4(const int* __restrict__ cnt, int* __restrict__ rp,
                        int* __restrict__ cur, int N){
  __shared__ int sh[1024];
  __shared__ int carry;
  int a = blockIdx.x;
  const int* c = cnt + a*N;
  int* r = rp + a*(N+1);
  if (threadIdx.x == 0) carry = 0;
  __syncthreads();
  for (int base = 0; base < N; base += 1024){
    int idx = base + threadIdx.x;
    int v = (idx < N) ? c[idx] : 0;
    sh[threadIdx.x] = v;
    __syncthreads();
    for (int off = 1; off < 1024; off <<= 1){
      int t = (threadIdx.x >= off) ? sh[threadIdx.x - off] : 0;
      __syncthreads();
      sh[threadIdx.x] += t;
      __syncthreads();
    }
    if (idx < N){
      int ex = carry + sh[threadIdx.x] - v;   // exclusive
      r[idx] = ex;
      cur[a*N + idx] = ex;
    }
    __syncthreads();
    if (threadIdx.x == 0) carry += sh[1023];
    __syncthreads();
  }
  if (threadIdx.x == 0) r[N] = carry;
}

__global__ void k_scatter(const int* __restrict__ ei, int* __restrict__ cur,
                          int* __restrict__ idx_gat,
                          int* __restrict__ idx_hgt, int* __restrict__ idx_hgt_dst,
                          int N, int E){
  int t = blockIdx.x*TPB + threadIdx.x;
  int EN = E + N;
  if (t < 3*E){
    int r = t / E, e = t - r*E;
    int src = ei[(r*2)*E + e];
    int dst = ei[(r*2+1)*E + e];
    int pg = atomicAdd(&cur[r*N + dst], 1);
    idx_gat[r*EN + pg] = src;
    int ph = atomicAdd(&cur[3*N + dst], 1);
    idx_hgt[ph] = r*N + src;           // packed (rel,src)
    idx_hgt_dst[ph] = dst;
  } else if (t < 3*E + 3*N){
    int tt = t - 3*E;
    int r = tt / N, i = tt - r*N;
    int pg = atomicAdd(&cur[r*N + i], 1);
    idx_gat[r*EN + pg] = i;            // self loop
  }
}

// ---------------- one-shot conversions: weights -> bf16 WT; x -> (hi,lo) bf16 ----------------
__device__ __forceinline__ void cvtw_one(const float* W, unsigned short* WT, int K, int u){
  int m = u / (96*K);
  int rem = u - m*96*K;
  int o = rem / K;
  int c = rem - o*K;
  WT[u] = f2bf(W[((size_t)m*K + c)*96 + o]);
}
__global__ void k_cvt_all(const float* __restrict__ x, const float* __restrict__ gat0_W,
                          const float* __restrict__ gat_W, const float* __restrict__ proj_W,
                          const float* __restrict__ hout_W,
                          unsigned short* __restrict__ x_hi, unsigned short* __restrict__ x_lo,
                          unsigned short* __restrict__ Wgat0T,
                          unsigned short* __restrict__ WgatT, unsigned short* __restrict__ WprojT,
                          unsigned short* __restrict__ WhoutT, int N){
  int t = blockIdx.x*TPB + threadIdx.x;
  int n0 = N*32, n1 = 3*96*32, n2 = 9*96*96, n3 = 2*96*32, n4 = 2*96*96;
  if (t < n0){
    float v = x[t];
    unsigned short hh = f2bf(v);
    x_hi[t] = hh;
    x_lo[t] = f2bf(v - bf2f(hh));
    return;
  }
  t -= n0;
  if (t < n1){ cvtw_one(gat0_W, Wgat0T, 32, t); return; }
  t -= n1;
  if (t < n2){ cvtw_one(gat_W, WgatT, 96, t); return; }
  t -= n2;
  if (t < n3){ cvtw_one(proj_W, WprojT, 32, t); return; }
  t -= n3;
  if (t < n4){ cvtw_one(hout_W, WhoutT, 96, t); }
}

// ---------------- split-A MFMA GEMM: 512 thr / 8 waves x 16 rows = 128-row tile ----------------
// Optional fused GAT att-dots (shfl butterfly) OR fused skip-mix + BN stats (mixh != nullptr).
__global__ __launch_bounds__(512) void k_gemm_mfma(
    const unsigned short* __restrict__ Ahi, const unsigned short* __restrict__ Alo,
    const unsigned short* __restrict__ WT,
    const float* __restrict__ bias, float* __restrict__ Cf,
    unsigned short* __restrict__ Cb, int bf16_from, int n, int K,
    const float* __restrict__ att, float* __restrict__ asrc, float* __restrict__ adst,
    const float* __restrict__ mixh, const float* __restrict__ skipp,
    float* __restrict__ stats){
  __shared__ unsigned short WlT[96*104];         // [col][K+8] padded
  __shared__ float sl1[96], sl2[96];
  const int Kp = K + 8;
  int mat = blockIdx.y;
  const unsigned short* Wm = WT + (size_t)mat*96*K;
  int chunks = 96*(K/8);
  for (int idx = threadIdx.x; idx < chunks; idx += 512){
    int col = idx/(K/8), kc = idx - col*(K/8);
    *reinterpret_cast<uint4*>(&WlT[col*Kp + kc*8]) =
      *reinterpret_cast<const uint4*>(&Wm[(size_t)col*K + kc*8]);
  }
  if (mixh && threadIdx.x < 96){ sl1[threadIdx.x] = 0.f; sl2[threadIdx.x] = 0.f; }
  __syncthreads();

  int wave = threadIdx.x >> 6, lane = threadIdx.x & 63;
  int l15 = lane & 15, l4 = lane >> 4;
  int rowbase = blockIdx.x*128 + wave*16;

  f32x4 acc[6];
  #pragma unroll
  for (int ct = 0; ct < 6; ct++){
    f32x4 z = {0.f, 0.f, 0.f, 0.f};
    acc[ct] = z;
  }

  int arow = rowbase + l15;
  for (int ks = 0; ks < K; ks += 32){
    short8 ahi, alo;
    if (arow < n){
      size_t off = (size_t)arow*K + ks + l4*8;
      ahi = *reinterpret_cast<const short8*>(Ahi + off);
      alo = *reinterpret_cast<const short8*>(Alo + off);
    } else {
      short8 z = {0,0,0,0,0,0,0,0};
      ahi = z; alo = z;
    }
    #pragma unroll
    for (int ct = 0; ct < 6; ct++){
      short8 b = *reinterpret_cast<const short8*>(&WlT[(ct*16 + l15)*Kp + ks + l4*8]);
      acc[ct] = __builtin_amdgcn_mfma_f32_16x16x32_bf16(alo, b, acc[ct], 0, 0, 0);
      acc[ct] = __builtin_amdgcn_mfma_f32_16x16x32_bf16(ahi, b, acc[ct], 0, 0, 0);
    }
  }

  if (att){   // fused GAT att-dots from raw fp32 accs (GAT gemm has bias=nullptr)
    const float* apS = att + mat*192;
    const float* apD = apS + 96;
    float wS[6], wD[6];
    #pragma unroll
    for (int ct = 0; ct < 6; ct++){ wS[ct] = apS[ct*16 + l15]; wD[ct] = apD[ct*16 + l15]; }
    #pragma unroll
    for (int r = 0; r < 4; r++){
      float s0 = 0.f, s1 = 0.f, d0 = 0.f, d1 = 0.f;
      #pragma unroll
      for (int ct = 0; ct < 3; ct++){
        float v = acc[ct][r];
        s0 += v*wS[ct]; d0 += v*wD[ct];
      }
      #pragma unroll
      for (int ct = 3; ct < 6; ct++){
        float v = acc[ct][r];
        s1 += v*wS[ct]; d1 += v*wD[ct];
      }
      #pragma unroll
      for (int m = 1; m < 16; m <<= 1){
        s0 += __shfl_xor(s0, m); s1 += __shfl_xor(s1, m);
        d0 += __shfl_xor(d0, m); d1 += __shfl_xor(d1, m);
      }
      if (l15 == 0){
        int row = rowbase + l4*4 + r;
        if (row < n){
          reinterpret_cast<float2*>(asrc)[(size_t)mat*n + row] = make_float2(s0, s1);
          reinterpret_cast<float2*>(adst)[(size_t)mat*n + row] = make_float2(d0, d1);
        }
      }
    }
  }

  // C/D layout (m89): col = lane&15, row = (lane>>4)*4 + reg
  if (mixh){   // hout path: skip-mix + BN stats epilogue (uniform work -> barrier safe)
    float sk = 1.f / (1.f + __expf(-skipp[0]));
    #pragma unroll
    for (int ct = 0; ct < 6; ct++){
      int col = ct*16 + l15;
      float bv = bias[mat*96 + col];
      #pragma unroll
      for (int r = 0; r < 4; r++){
        int row = rowbase + l4*4 + r;
        if (row < n){
          float v = acc[ct][r] + bv;
          v = sk*v + (1.f - sk)*mixh[(size_t)row*96 + col];
          Cf[(size_t)row*96 + col] = v;
          atomicAdd(&sl1[col], v);
          atomicAdd(&sl2[col], v*v);
        }
      }
    }
    __syncthreads();
    if (threadIdx.x < 96){
      atomicAdd(&stats[threadIdx.x], sl1[threadIdx.x]);
      atomicAdd(&stats[96 + threadIdx.x], sl2[threadIdx.x]);
    }
  } else {
    bool as_bf = (mat >= bf16_from);
    #pragma unroll
    for (int ct = 0; ct < 6; ct++){
      int col = ct*16 + l15;
      float bv = bias ? bias[mat*96 + col] : 0.f;
      #pragma unroll
      for (int r = 0; r < 4; r++){
        int row = rowbase + l4*4 + r;
        if (row < n){
          float v = acc[ct][r] + bv;
          if (as_bf)
            Cb[(size_t)(mat - bf16_from)*n*96 + (size_t)row*96 + col] = f2bf(v);
          else
            Cf[(size_t)mat*n*96 + (size_t)row*96 + col] = v;
        }
      }
    }
  }
}

// ---------------- HGT effective-weight prep (both layers, one launch) ----------
__global__ void k_prep(const float* __restrict__ kqv_W, const float* __restrict__ kqv_b,
                       const float* __restrict__ a_rel, const float* __restrict__ m_rel,
                       const float* __restrict__ p_rel,
                       unsigned short* __restrict__ WbigT, float* __restrict__ bbig){
  int layer = blockIdx.y;
  const float* kW   = kqv_W + (size_t)layer*3*96*96;
  const float* kb   = kqv_b + layer*3*96;
  const float* arel = a_rel + (size_t)layer*3*6*256;
  const float* mrel = m_rel + (size_t)layer*3*6*256;
  const float* prel = p_rel + layer*18;
  unsigned short* WT = WbigT + (size_t)layer*7*96*96;
  float* bb = bbig + layer*7*96;
  int t = blockIdx.x*TPB + threadIdx.x;
  const int total = 7*96*96;
  if (t < total){
    int m = t / (96*96);
    int rem = t - m*(96*96);
    int o = rem / 96;        // output col
    int c = rem - o*96;      // input k
    float val;
    if (m == 0){
      val = kW[(size_t)96*96 + c*96 + o];            // q weights
    } else {
      int r = (m - 1) % 3;
      bool isV = m >= 4;
      const float* base = isV ? mrel : arel;         // [3][6][16][16]
      const float* wsrc = kW + (size_t)(isV ? 2 : 0)*96*96;
      int h = o >> 4, ff = o & 15;
      float s = 0.f;
      #pragma unroll
      for (int d = 0; d < 16; d++)
        s += wsrc[c*96 + h*16 + d] * base[(size_t)((r*6 + h)*16 + d)*16 + ff];
      if (!isV) s *= 0.25f * prel[r*6 + h];
      val = s;
    }
    WT[t] = f2bf(val);       // t == (m*96 + o)*96 + c
  } else if (t < total + 7*96){
    int tt = t - total;
    int m = tt / 96, o = tt - m*96;
    float val;
    if (m == 0){
      val = kb[96 + o];
    } else {
      int r = (m - 1) % 3;
      bool isV = m >= 4;
      const float* base = isV ? mrel : arel;
      const float* bsrc = kb + (isV ? 2 : 0)*96;
      int h = o >> 4, ff = o & 15;
      float s = 0.f;
      #pragma unroll
      for (int d = 0; d < 16; d++)
        s += bsrc[h*16 + d] * base[(size_t)((r*6 + h)*16 + d)*16 + ff];
      if (!isV) s *= 0.25f * prel[r*6 + h];
      val = s;
    }
    bb[tt] = val;
  }
}

// ---------------- GAT fused v4 (R16-proven): wave/node; 3-rel prefetch + unroll-4 j-loop ----
__global__ __launch_bounds__(TPB) void k_gat_fused(const float* __restrict__ asrc,
                        const float* __restrict__ adst, const unsigned short* __restrict__ hp,
                        const int* __restrict__ rowptr, const int* __restrict__ idxg,
                        const float* __restrict__ b3, float* __restrict__ pre,
                        int n, int EN){
  int wid = (blockIdx.x*TPB + threadIdx.x) >> 6;   // wave id = node
  if (wid >= n) return;
  int lane = threadIdx.x & 63;

  // phase 1: prefetch all 3 relations' first batches (loads issue together)
  int s0[3], s1[3], cnt0[3], src0[3];
  float2 av0[3], adv[3];
  #pragma unroll
  for (int r = 0; r < 3; r++){
    const int* rp = rowptr + r*(n+1);
    s0[r] = rp[wid]; s1[r] = rp[wid+1];
    cnt0[r] = min(64, s1[r] - s0[r]);
    adv[r] = (reinterpret_cast<const float2*>(adst) + (size_t)r*n)[wid];
  }
  #pragma unroll
  for (int r = 0; r < 3; r++)
    src0[r] = (lane < cnt0[r]) ? idxg[(size_t)r*EN + s0[r] + lane] : 0;
  #pragma unroll
  for (int r = 0; r < 3; r++)
    av0[r] = (lane < cnt0[r]) ? (reinterpret_cast<const float2*>(asrc) + (size_t)r*n)[src0[r]]
                              : make_float2(0.f, 0.f);

  float comb_a = 0.f, comb_b = 0.f;
  #pragma unroll
  for (int r = 0; r < 3; r++){
    const unsigned short* hpb = hp + (size_t)r*n*96;
    float w0_l = 0.f, w1_l = 0.f;
    if (lane < cnt0[r]){
      w0_l = __expf(fminf(lrelu(av0[r].x + adv[r].x), 80.f));
      w1_l = __expf(fminf(lrelu(av0[r].y + adv[r].y), 80.f));
    }
    float acc_a = 0.f, acc_b = 0.f, ss0 = 0.f, ss1 = 0.f;
    int cnt = cnt0[r];
    int src_l = src0[r];
    int base = s0[r];
    while (true){
      int j = 0;
      for (; j + 4 <= cnt; j += 4){
        int sa = __shfl(src_l, j),   sb = __shfl(src_l, j+1);
        int sc = __shfl(src_l, j+2), sd = __shfl(src_l, j+3);
        const unsigned short* ra = hpb + (size_t)sa*96;
        const unsigned short* rb = hpb + (size_t)sb*96;
        const unsigned short* rc = hpb + (size_t)sc*96;
        const unsigned short* rd = hpb + (size_t)sd*96;
        float vaa = bf2f(ra[lane]), vab = bf2f(rb[lane]);
        float vac = bf2f(rc[lane]), vad = bf2f(rd[lane]);
        float vba = 0.f, vbb = 0.f, vbc = 0.f, vbd = 0.f;
        if (lane < 32){
          vba = bf2f(ra[64+lane]); vbb = bf2f(rb[64+lane]);
          vbc = bf2f(rc[64+lane]); vbd = bf2f(rd[64+lane]);
        }
        float w0a = __shfl(w0_l, j),   w1a = __shfl(w1_l, j);
        float w0b = __shfl(w0_l, j+1), w1b = __shfl(w1_l, j+1);
        float w0c = __shfl(w0_l, j+2), w1c = __shfl(w1_l, j+2);
        float w0d = __shfl(w0_l, j+3), w1d = __shfl(w1_l, j+3);
        float waa = (lane < 48) ? w0a : w1a;
        float wab = (lane < 48) ? w0b : w1b;
        float wac = (lane < 48) ? w0c : w1c;
        float wad = (lane < 48) ? w0d : w1d;
        acc_a += waa*vaa; acc_b += w1a*vba; ss0 += w0a; ss1 += w1a;
        acc_a += wab*vab; acc_b += w1b*vbb; ss0 += w0b; ss1 += w1b;
        acc_a += wac*vac; acc_b += w1c*vbc; ss0 += w0c; ss1 += w1c;
        acc_a += wad*vad; acc_b += w1d*vbd; ss0 += w0d; ss1 += w1d;
      }
      for (; j < cnt; j++){
        int sa = __shfl(src_l, j);
        const unsigned short* ra = hpb + (size_t)sa*96;
        float vaa = bf2f(ra[lane]);
        float vba = (lane < 32) ? bf2f(ra[64+lane]) : 0.f;
        float w0a = __shfl(w0_l, j), w1a = __shfl(w1_l, j);
        float waa = (lane < 48) ? w0a : w1a;
        acc_a += waa*vaa; acc_b += w1a*vba; ss0 += w0a; ss1 += w1a;
      }
      base += 64;
      if (base >= s1[r]) break;
      cnt = min(64, s1[r] - base);         // rare: degree > 64
      src_l = 0; w0_l = 0.f; w1_l = 0.f;
      if (lane < cnt){
        src_l = idxg[(size_t)r*EN + base + lane];
        float2 av = (reinterpret_cast<const float2*>(asrc) + (size_t)r*n)[src_l];
        w0_l = __expf(fminf(lrelu(av.x + adv[r].x), 80.f));
        w1_l = __expf(fminf(lrelu(av.y + adv[r].y), 80.f));
      }
    }
    comb_a += acc_a / ((lane < 48) ? ss0 : ss1);   // self-loop => non-empty
    comb_b += acc_b / ss1;
  }
  comb_a += b3[lane] + b3[96 + lane] + b3[192 + lane];
  float* pr = pre + (size_t)wid*96;
  pr[lane] = comb_a;
  if (lane < 32){
    comb_b += b3[64 + lane] + b3[160 + lane] + b3[256 + lane];
    pr[64 + lane] = comb_b;
  }
}

// ---------------- BN stats over pre: grid-stride sum/sumsq ----------------
__global__ void k_stats(const float* __restrict__ pre, float* __restrict__ stats, int total){
  __shared__ float s1[96], s2[96];
  if (threadIdx.x < 96){ s1[threadIdx.x] = 0.f; s2[threadIdx.x] = 0.f; }
  __syncthreads();
  int idx0 = blockIdx.x*TPB*8 + threadIdx.x;
  for (int it = 0; it < 8; it++){
    int idx = idx0 + it*TPB;
    if (idx < total){
      int c = idx % 96;
      float v = pre[idx];
      atomicAdd(&s1[c], v);
      atomicAdd(&s2[c], v*v);
    }
  }
  __syncthreads();
  if (threadIdx.x < 96){
    atomicAdd(&stats[threadIdx.x], s1[threadIdx.x]);
    atomicAdd(&stats[96 + threadIdx.x], s2[threadIdx.x]);
  }
}

// ---------------- apply: BN finalize + lrelu; writes fp32 h AND (hi,lo) bf16 h ----------------
__global__ void k_apply2(float* __restrict__ h, unsigned short* __restrict__ h_hi,
                         unsigned short* __restrict__ h_lo,
                         const float* __restrict__ pre,
                         const float* __restrict__ stats, const float* __restrict__ gamma,
                         const float* __restrict__ beta, const float* __restrict__ inj,
                         int res, int total, float inv_n){
  int idx = blockIdx.x*TPB + threadIdx.x;
  if (idx >= total) return;
  int c = idx % 96;
  float mean = stats[c] * inv_n;
  float var  = stats[96 + c] * inv_n - mean*mean;
  float sc   = gamma[c] * rsqrtf(var + 1e-5f);
  float sh   = beta[c] - mean*sc;
  float v = sc*pre[idx] + sh;
  if (inj) v += inj[idx];
  if (res) v += h[idx];
  v = lrelu(v);
  h[idx] = v;
  unsigned short hh = f2bf(v);
  h_hi[idx] = hh;
  h_lo[idx] = f2bf(v - bf2f(hh));
}

// ---------------- HGT phase A: per-(slot,head) edge weights (scale pre-folded) ----------------
__global__ void k_hgt_w(const float* __restrict__ q, const float* __restrict__ Kb,
                        const int* __restrict__ idxh, const int* __restrict__ idxh_dst,
                        float* __restrict__ wbuf, int n, int totE){
  int t = blockIdx.x*TPB + threadIdx.x;
  if (t >= totE*6) return;
  int slot = t / 6, h = t - slot*6;
  int packed = idxh[slot];
  int dst = idxh_dst[slot];
  const float4* kp = reinterpret_cast<const float4*>(Kb + (size_t)packed*96 + h*16);
  const float4* qp = reinterpret_cast<const float4*>(q + (size_t)dst*96 + h*16);
  float dot = 0.f;
  #pragma unroll
  for (int w = 0; w < 4; w++){
    float4 kv = kp[w], qv = qp[w];
    dot += kv.x*qv.x + kv.y*qv.y + kv.z*qv.z + kv.w*qv.w;
  }
  wbuf[t] = __expf(fminf(dot, 80.f));
}

// ---------------- HGT fused gather v2: wave per node; unroll-4 j-loop; bf16 V; + GELU ----------
__global__ __launch_bounds__(TPB) void k_hgt_fused(const float* __restrict__ wbuf,
                        const unsigned short* __restrict__ Vb, const int* __restrict__ rp4,
                        const int* __restrict__ idxh,
                        unsigned short* __restrict__ aux_hi, unsigned short* __restrict__ aux_lo,
                        int n){
  int wid = (blockIdx.x*TPB + threadIdx.x) >> 6;
  if (wid >= n) return;
  int lane = threadIdx.x & 63;
  const int* rp = rp4 + 3*(n+1);
  int s0 = rp[wid], s1 = rp[wid+1];
  int ha = lane >> 4;                         // head for col=lane (0..3)
  int hb = lane >> 4;                         // head sel for col 64+lane
  float acc_a = 0.f, acc_b = 0.f, ss_a = 0.f, ss_b = 0.f;
  for (int base = s0; base < s1; base += 64){
    int cnt = min(64, s1 - base);
    int pk = 0; float w0=0.f,w1=0.f,w2=0.f,w3=0.f,w4=0.f,w5=0.f;
    if (lane < cnt){
      int slot = base + lane;
      pk = idxh[slot];
      const float2* wp = reinterpret_cast<const float2*>(wbuf + (size_t)slot*6);
      float2 p0 = wp[0], p1 = wp[1], p2 = wp[2];
      w0=p0.x; w1=p0.y; w2=p1.x; w3=p1.y; w4=p2.x; w5=p2.y;
    }
    int j = 0;
    for (; j + 4 <= cnt; j += 4){
      int pa = __shfl(pk, j),   pb = __shfl(pk, j+1);
      int pc = __shfl(pk, j+2), pd = __shfl(pk, j+3);
      const unsigned short* ra = Vb + (size_t)pa*96;
      const unsigned short* rb = Vb + (size_t)pb*96;
      const unsigned short* rc = Vb + (size_t)pc*96;
      const unsigned short* rd = Vb + (size_t)pd*96;
      float vaa = bf2f(ra[lane]), vab = bf2f(rb[lane]);
      float vac = bf2f(rc[lane]), vad = bf2f(rd[lane]);
      float vba = 0.f, vbb = 0.f, vbc = 0.f, vbd = 0.f;
      if (lane < 32){
        vba = bf2f(ra[64+lane]); vbb = bf2f(rb[64+lane]);
        vbc = bf2f(rc[64+lane]); vbd = bf2f(rd[64+lane]);
      }
      #pragma unroll
      for (int u = 0; u < 4; u++){
        int jj = j + u;
        float b0=__shfl(w0,jj), b1=__shfl(w1,jj), b2=__shfl(w2,jj),
              b3v=__shfl(w3,jj), b4=__shfl(w4,jj), b5=__shfl(w5,jj);
        float va = (u==0)?vaa:(u==1)?vab:(u==2)?vac:vad;
        float vb = (u==0)?vba:(u==1)?vbb:(u==2)?vbc:vbd;
        float wa = (ha==0) ? b0 : ((ha==1) ? b1 : ((ha==2) ? b2 : b3v));
        float wb = (hb == 0) ? b4 : b5;
        acc_a += wa*va; ss_a += wa;
        acc_b += wb*vb; ss_b += wb;
      }
    }
    for (; j < cnt; j++){
      int packed = __shfl(pk, j);
      float b0=__shfl(w0,j), b1=__shfl(w1,j), b2=__shfl(w2,j),
            b3v=__shfl(w3,j), b4=__shfl(w4,j), b5=__shfl(w5,j);
      const unsigned short* row = Vb + (size_t)packed*96;
      float va = bf2f(row[lane]);
      float vb = (lane < 32) ? bf2f(row[64 + lane]) : 0.f;
      float wa = (ha==0) ? b0 : ((ha==1) ? b1 : ((ha==2) ? b2 : b3v));
      float wb = (hb == 0) ? b4 : b5;
      acc_a += wa*va; ss_a += wa;
      acc_b += wb*vb; ss_b += wb;
    }
  }
  float xa = (s1 > s0) ? acc_a/ss_a : 0.f;
  float ga = 0.5f*xa*(1.f + erff(xa*0.70710678118654752f));
  size_t base_o = (size_t)wid*96;
  unsigned short hh = f2bf(ga);
  aux_hi[base_o + lane] = hh;
  aux_lo[base_o + lane] = f2bf(ga - bf2f(hh));
  if (lane < 32){
    float xb = (s1 > s0) ? acc_b/ss_b : 0.f;
    float gb = 0.5f*xb*(1.f + erff(xb*0.70710678118654752f));
    unsigned short hb2 = f2bf(gb);
    aux_hi[base_o + 64 + lane] = hb2;
    aux_lo[base_o + 64 + lane] = f2bf(gb - bf2f(hb2));
  }
}

// ---------------- final linear ----------------
__global__ void k_final_lin(const float* __restrict__ h, const float* __restrict__ w,
                            const float* __restrict__ b, float* __restrict__ out, int N){
  int i = blockIdx.x*TPB + threadIdx.x;
  if (i >= N) return;
  const float4* hr = reinterpret_cast<const float4*>(h + (size_t)i*96);
  const float4* wr = reinterpret_cast<const float4*>(w);
  float acc = 0.f;
  #pragma unroll
  for (int c = 0; c < 24; c++){
    float4 a = hr[c], q = wr[c];
    acc += a.x*q.x + a.y*q.y + a.z*q.z + a.w*q.w;
  }
  out[i] = acc + b[0];
}

// =====================================================================
extern "C" void kernel_launch(void* const* d_in, const int* in_sizes, int n_in,
                              void* d_out, int out_size, void* d_ws, size_t ws_size,
                              hipStream_t stream){
  const float* x        = (const float*)d_in[0];
  const int*   ei       = (const int*)  d_in[1];
  const float* gat0_W   = (const float*)d_in[2];
  const float* gat0_att = (const float*)d_in[3];
  const float* gat0_b   = (const float*)d_in[4];
  const float* gat_W    = (const float*)d_in[5];
  const float* gat_att  = (const float*)d_in[6];
  const float* gat_b    = (const float*)d_in[7];
  const float* bn_g     = (const float*)d_in[8];
  const float* bn_b     = (const float*)d_in[9];
  const float* kqv_W    = (const float*)d_in[10];
  const float* kqv_b    = (const float*)d_in[11];
  const float* a_rel    = (const float*)d_in[12];
  const float* m_rel    = (const float*)d_in[13];
  const float* p_rel    = (const float*)d_in[14];
  const float* hout_W   = (const float*)d_in[15];
  const float* hout_b   = (const float*)d_in[16];
  const float* skip     = (const float*)d_in[17];
  const float* proj_W   = (const float*)d_in[18];
  const float* proj_b   = (const float*)d_in[19];
  const float* lin_W    = (const float*)d_in[20];
  const float* lin_b    = (const float*)d_in[21];
  float* out = (float*)d_out;

  const int N = in_sizes[0] / 32;
  const int E = in_sizes[1] / 6;
  const int EN = E + N;
  const size_t NH = (size_t)N * 96;
  const int nh = (int)NH;
  const float inv_n = 1.f / (float)N;

  // ---- workspace layout (floats, then bf16, then ints) ----
  float* f = (float*)d_ws;
  float* h_buf = f;  f += NH;
  float* pre   = f;  f += NH;        // aliased as wbuf (HGT phase A->B window)
  float* big   = f;  f += 4*NH;      // HGT fp32: q, K0..2
  float* inj2  = f;  f += 2*NH;      // proj injections (precomputed)
  float* asrc  = f;  f += (size_t)3*N*2;
  float* adst  = f;  f += (size_t)3*N*2;
  float* stats = f;  f += 6*192;     // 6 BN slots of (sum[96], sumsq[96])
  float* bbig  = f;  f += 2*7*96;
  unsigned short* us = (unsigned short*)f;
  unsigned short* gbf    = us;  us += 3*NH;        // bf16 gather src: GAT hp[3] | HGT V[3]
  unsigned short* h_hi   = us;  us += NH;
  unsigned short* h_lo   = us;  us += NH;
  unsigned short* x_hi   = us;  us += (size_t)N*32;
  unsigned short* x_lo   = us;  us += (size_t)N*32;
  unsigned short* aux_hi = us;  us += NH;
  unsigned short* aux_lo = us;  us += NH;
  unsigned short* WbigT  = us;  us += 2*7*96*96;
  unsigned short* Wgat0T = us;  us += 3*96*32;
  unsigned short* WgatT  = us;  us += 9*96*96;
  unsigned short* WprojT = us;  us += 2*96*32;
  unsigned short* WhoutT = us;  us += 2*96*96;
  us += (us - (unsigned short*)f) & 1;             // realign to 4B
  int* ip = (int*)us;
  int* cnt     = ip;  ip += 4*N;
  int* rowptr  = ip;  ip += 4*(N+1);
  int* cursor  = ip;  ip += 4*N;
  int* idx_gat     = ip;  ip += 3*EN;
  int* idx_hgt     = ip;  ip += 3*E;
  int* idx_hgt_dst = ip;  ip += 3*E;
  float* wbuf = pre;                 // 3E*6 = 1.8M floats <= NH

  auto g1 = [](int n){ return dim3((n + TPB - 1)/TPB); };
  const int gx2 = (N + 127)/128;              // MFMA GEMM row-tiles
  const dim3 mg3(gx2, 3);                     // 3-mat MFMA grid (GAT)
  const dim3 mg7(gx2, 7);                     // 7-mat MFMA grid (HGT qKV)
  const dim3 mg2(gx2, 2);                     // 2-mat MFMA grid (proj)
  const dim3 mg1(gx2, 1);                     // 1-mat MFMA grid (hout)
  const dim3 pg(g1(7*96*96 + 7*96).x, 2);     // prep grid (both HGT layers)
  const int cs_blocks = (nh + TPB*8 - 1)/(TPB*8);
  const int wave_blocks = (N + 3)/4;          // 4 waves (nodes) per 256-block
  const int cvt_total = N*32 + 3*96*32 + 9*96*96 + 2*96*32 + 2*96*96;

  // ---- CSR build + stats zero + one-time conversions + prep + proj injections ----
  hipMemsetAsync(stats, 0, 6*192*sizeof(float), stream);
  k_init_cnt<<<g1(4*N),     TPB, 0, stream>>>(cnt, N);
  k_count   <<<g1(3*E),     TPB, 0, stream>>>(ei, cnt, N, E);
  k_scan4   <<<4,          1024, 0, stream>>>(cnt, rowptr, cursor, N);
  k_scatter <<<g1(3*E+3*N), TPB, 0, stream>>>(ei, cursor, idx_gat, idx_hgt, idx_hgt_dst, N, E);
  k_cvt_all <<<g1(cvt_total), TPB, 0, stream>>>(x, gat0_W, gat_W, proj_W, hout_W,
                                                x_hi, x_lo, Wgat0T, WgatT, WprojT, WhoutT, N);
  k_prep    <<<pg, TPB, 0, stream>>>(kqv_W, kqv_b, a_rel, m_rel, p_rel, WbigT, bbig);
  k_gemm_mfma<<<mg2, 512, 0, stream>>>(x_hi, x_lo, WprojT, proj_b, inj2, nullptr, 99, N, 32,
                                       nullptr, nullptr, nullptr, nullptr, nullptr, nullptr);

  auto run_hgt = [&](int idx, int bnidx){
    // mats 0..3 (q,K0..2) -> fp32 big; mats 4..6 (V0..2) -> bf16 gbf
    k_gemm_mfma<<<mg7, 512, 0, stream>>>(h_hi, h_lo, WbigT + (size_t)idx*7*96*96,
                                         bbig + idx*7*96, big, gbf, 4, N, 96,
                                         nullptr, nullptr, nullptr, nullptr, nullptr, nullptr);
    k_hgt_w    <<<g1(3*E*6), TPB, 0, stream>>>(big, big + NH, idx_hgt, idx_hgt_dst, wbuf, N, 3*E);
    k_hgt_fused<<<wave_blocks, TPB, 0, stream>>>(wbuf, gbf, rowptr, idx_hgt,
                                                 aux_hi, aux_lo, N);
    // hout GEMM with fused skip-mix + BN stats epilogue
    k_gemm_mfma<<<mg1, 512, 0, stream>>>(aux_hi, aux_lo, WhoutT + (size_t)idx*96*96,
                                         hout_b + idx*96, pre, nullptr, 99, N, 96,
                                         nullptr, nullptr, nullptr,
                                         h_buf, skip + idx, stats + bnidx*192);
    k_apply2   <<<g1(nh), TPB, 0, stream>>>(h_buf, h_hi, h_lo, pre, stats + bnidx*192,
                                            bn_g + bnidx*96, bn_b + bnidx*96, nullptr, 1, nh, inv_n);
  };

  // ---- GAT layer 0 (input dim 32, no residual) ----
  k_gemm_mfma<<<mg3, 512, 0, stream>>>(x_hi, x_lo, Wgat0T, nullptr, nullptr, gbf, 0, N, 32,
                                       gat0_att, asrc, adst, nullptr, nullptr, nullptr);
  k_gat_fused<<<wave_blocks, TPB, 0, stream>>>(asrc, adst, gbf, rowptr, idx_gat, gat0_b, pre, N, EN);
  k_stats    <<<cs_blocks, TPB, 0, stream>>>(pre, stats, nh);
  k_apply2   <<<g1(nh), TPB, 0, stream>>>(h_buf, h_hi, h_lo, pre, stats,
                                          bn_g, bn_b, nullptr, 0, nh, inv_n);

  // ---- GAT layers 1..3 ----
  for (int i = 0; i < 3; i++){
    int li = i + 1;
    int bnidx = 1 + i;
    k_gemm_mfma<<<mg3, 512, 0, stream>>>(h_hi, h_lo, WgatT + (size_t)i*3*96*96, nullptr,
                                         nullptr, gbf, 0, N, 96,
                                         gat_att + i*3*192, asrc, adst, nullptr, nullptr, nullptr);
    k_gat_fused<<<wave_blocks, TPB, 0, stream>>>(asrc, adst, gbf, rowptr, idx_gat,
                                                 gat_b + i*3*96, pre, N, EN);
    k_stats    <<<cs_blocks, TPB, 0, stream>>>(pre, stats + bnidx*192, nh);
    const float* inj = (li >= 2) ? (inj2 + (size_t)(li-2)*NH) : nullptr;
    k_apply2<<<g1(nh), TPB, 0, stream>>>(h_buf, h_hi, h_lo, pre, stats + bnidx*192,
                                         bn_g + bnidx*96, bn_b + bnidx*96, inj, 1, nh, inv_n);
    if (li == 1) run_hgt(0, 4);
  }
  run_hgt(1, 5);

  k_final_lin<<<g1(N), TPB, 0, stream>>>(h_buf, lin_W, lin_b, out, N);
}